// Round 6
// baseline (204.276 us; speedup 1.0000x reference)
//
#include <hip/hip_runtime.h>
#include <hip/hip_bf16.h>

// FeatureProcessingBlock: per 64x64 window, Out = sum_t Cs_t^T ( Hs_t^T @ X_c @ Ws_t )
// R6: c=wave in A AND B -> B consumes own-wave A output (Y1F wave-private, no A->B
//     barrier, merged long phase). hsf -> LDS table Hf (all mt per wave). Zb 64B rows,
//     k=c*4+t, aligned u64 writes + b128 reads, (px&3)<<4 XOR swizzle; Cf bakes zeros
//     at t==3 so C-phase has no divergence. 2 barriers/chunk.

typedef __attribute__((ext_vector_type(8))) short short8;
typedef __attribute__((ext_vector_type(4))) short short4v;
typedef __attribute__((ext_vector_type(4))) float float4v;

#define SMEM_BYTES 157696
// Y1F @0:      [8 wave][3 t][2 sv][64 lane][16 B] = 49152   (wave-private slices)
// Zb  @49152:  [1024 px][64 B]  (k=c*4+t at byte 2k, XOR (px&3)<<4) = 65536
// Hf  @114688: [4 mt][3 t][2 sv][64 lane][16 B] = 24576
// Cf  @139264: [18 s*m][16 lc][64 B] (XOR (lc&3)<<4) = 18432

static __device__ __forceinline__ unsigned short f2bf(float f) {
  return __builtin_bit_cast(unsigned short, __float2bfloat16(f));
}
static __device__ __forceinline__ unsigned long long pk4(float a, float b, float c, float d) {
  unsigned long long lo = (unsigned int)((unsigned int)f2bf(a) | ((unsigned int)f2bf(b) << 16));
  unsigned long long hi = (unsigned int)((unsigned int)f2bf(c) | ((unsigned int)f2bf(d) << 16));
  return lo | (hi << 32);
}

__global__ __launch_bounds__(512, 2)
void fpb6(const float* __restrict__ x, const float* __restrict__ Ws,
          const float* __restrict__ Hsm, const float* __restrict__ Cs,
          float* __restrict__ out) {
  extern __shared__ char smem[];
  char* Y1F = smem;
  char* Zb  = smem + 49152;
  char* Hf  = smem + 114688;
  char* Cf  = smem + 139264;

  int wid = (blockIdx.x & 7) * 128 + (blockIdx.x >> 3);  // XCD swizzle
  int window = wid >> 2, tile = wid & 3;
  int b = window >> 6, p = (window >> 3) & 7, q = window & 7;
  int j0 = tile * 16;

  int tid = threadIdx.x, lane = tid & 63, wave = tid >> 6;
  int lq = lane >> 4, lc = lane & 15;

  // ---- init: Hf table (A-frags of Hs^T for all mt) ----
  for (int j = wave; j < 24; j += 8) {       // j = mt*6 + t*2 + sv
    int mt = j / 6, r6 = j - 6 * mt, t = r6 >> 1, sv = r6 & 1;
    short8 v;
    #pragma unroll
    for (int e = 0; e < 8; ++e) {
      int h = 32 * sv + 8 * lq + e;
      v[e] = (short)f2bf(Hsm[t * 4096 + h * 64 + 16 * mt + lc]);
    }
    *(short8*)(Hf + (j * 64 + lane) * 16) = v;
  }
  // ---- init: Cf table (C-phase A-frags; k=c*4+t, zeros baked at t==3) ----
  for (int row = wave; row < 18; row += 8) { // row = s*3 + m
    int ss = row / 3, m = row - 3 * ss;
    short8 v;
    #pragma unroll
    for (int e = 0; e < 8; ++e) {
      int k = 8 * lq + e, c = k >> 2, t = k & 3;
      v[e] = (t < 3) ? (short)f2bf(Cs[t * 2304 + (8 * ss + c) * 48 + 16 * m + lc])
                     : (short)0;
    }
    *(short8*)(Cf + ((((row * 16 + lc) * 64) + 16 * lq) ^ ((lc & 3) << 4))) = v;
  }

  // ---- persistent Ws fragments (B-operand of A-phase) ----
  short8 wsf[3][2];
  #pragma unroll
  for (int t = 0; t < 3; ++t)
    #pragma unroll
    for (int sv = 0; sv < 2; ++sv) {
      short8 aa;
      #pragma unroll
      for (int e = 0; e < 8; ++e) {
        int k = 32 * sv + 8 * lq + e;
        aa[e] = (short)f2bf(Ws[t * 4096 + k * 64 + j0 + lc]);
      }
      wsf[t][sv] = aa;
    }

  float4v acc[3][8];
  #pragma unroll
  for (int m = 0; m < 3; ++m)
    #pragma unroll
    for (int i = 0; i < 8; ++i) acc[m][i] = float4v{0.f, 0.f, 0.f, 0.f};

  // A-stage: wave = c (within chunk); rows 16*mA+lc, cols 8*lq(+32)
  const float* xbase = x + (((size_t)b * 48) * 512 + p * 64) * 512 + q * 64
                         + (size_t)wave * 262144 + (size_t)lc * 512 + 8 * lq;

  float4v fin[2][8];   // two half-chunk prefetch slots
  #pragma unroll
  for (int h = 0; h < 2; ++h) {
    const float* src = xbase + (size_t)(32 * h) * 512;
    #pragma unroll
    for (int j2 = 0; j2 < 2; ++j2) {
      const float* r = src + (size_t)(16 * j2) * 512;
      fin[h][4*j2+0] = *(const float4v*)(r);
      fin[h][4*j2+1] = *(const float4v*)(r + 4);
      fin[h][4*j2+2] = *(const float4v*)(r + 32);
      fin[h][4*j2+3] = *(const float4v*)(r + 36);
    }
  }

  __syncthreads();   // Hf + Cf ready

  char* y1w = Y1F + wave * 6144;   // this wave's private slice

  for (int s = 0; s < 6; ++s) {
    // ======== merged A+B phase (no internal barrier) ========
    // A: Y1[c=wave] = X_c @ Ws_t, D-frags stored frag-major into private slice
    #pragma unroll
    for (int h = 0; h < 2; ++h) {
      short8 af[4];
      #pragma unroll
      for (int j2 = 0; j2 < 2; ++j2) {
        short8 a0, a1;
        #pragma unroll
        for (int e2 = 0; e2 < 4; ++e2) {
          a0[e2]   = (short)f2bf(fin[h][4*j2+0][e2]);
          a0[4+e2] = (short)f2bf(fin[h][4*j2+1][e2]);
          a1[e2]   = (short)f2bf(fin[h][4*j2+2][e2]);
          a1[4+e2] = (short)f2bf(fin[h][4*j2+3][e2]);
        }
        af[2*j2] = a0; af[2*j2+1] = a1;
      }
      if (s < 5) {  // refill this slot for chunk s+1 (full-chunk latency cover)
        const float* src = xbase + (size_t)(s + 1) * 2097152 + (size_t)(32 * h) * 512;
        #pragma unroll
        for (int j2 = 0; j2 < 2; ++j2) {
          const float* r = src + (size_t)(16 * j2) * 512;
          fin[h][4*j2+0] = *(const float4v*)(r);
          fin[h][4*j2+1] = *(const float4v*)(r + 4);
          fin[h][4*j2+2] = *(const float4v*)(r + 32);
          fin[h][4*j2+3] = *(const float4v*)(r + 36);
        }
      }
      #pragma unroll
      for (int j2 = 0; j2 < 2; ++j2) {
        int mA  = 2 * h + j2;
        int sv  = mA >> 1;
        int lqp = (2 * mA + (lq >> 1)) & 3;   // B-frag lane group (verified in R5)
        int eo  = (lq & 1) * 8;
        #pragma unroll
        for (int t = 0; t < 3; ++t) {
          float4v d = {0.f, 0.f, 0.f, 0.f};
          d = __builtin_amdgcn_mfma_f32_16x16x32_bf16(af[2*j2],   wsf[t][0], d, 0, 0, 0);
          d = __builtin_amdgcn_mfma_f32_16x16x32_bf16(af[2*j2+1], wsf[t][1], d, 0, 0, 0);
          short4v pv;
          pv[0] = (short)f2bf(d[0]); pv[1] = (short)f2bf(d[1]);
          pv[2] = (short)f2bf(d[2]); pv[3] = (short)f2bf(d[3]);
          *(short4v*)(y1w + (t * 2 + sv) * 1024 + (lqp * 16 + lc) * 16 + eo) = pv;
        }
      }
    }

    // B: V[c=wave][all H'] = Hs_t^T @ Y1 (reads OWN slice; lgkmcnt orders RAW)
    {
      short8 y0[3], y1[3];
      #pragma unroll
      for (int t = 0; t < 3; ++t) {
        y0[t] = *(const short8*)(y1w + (t * 2 + 0) * 1024 + lane * 16);
        y1[t] = *(const short8*)(y1w + (t * 2 + 1) * 1024 + lane * 16);
      }
      #pragma unroll
      for (int mt = 0; mt < 4; ++mt) {
        float4v dB[3];
        #pragma unroll
        for (int t = 0; t < 3; ++t) {
          short8 hf0 = *(const short8*)(Hf + ((mt * 6 + t * 2 + 0) * 64 + lane) * 16);
          short8 hf1 = *(const short8*)(Hf + ((mt * 6 + t * 2 + 1) * 64 + lane) * 16);
          float4v dd = {0.f, 0.f, 0.f, 0.f};
          dd = __builtin_amdgcn_mfma_f32_16x16x32_bf16(hf0, y0[t], dd, 0, 0, 0);
          dd = __builtin_amdgcn_mfma_f32_16x16x32_bf16(hf1, y1[t], dd, 0, 0, 0);
          dB[t] = dd;
        }
        #pragma unroll
        for (int r = 0; r < 4; ++r) {
          int px = (16 * mt + 4 * lq + r) * 16 + lc;
          *(unsigned long long*)(Zb + ((px * 64 + 8 * wave) ^ ((px & 3) << 4))) =
              pk4(dB[0][r], dB[1][r], dB[2][r], 0.f);
        }
      }
    }
    __syncthreads();   // Zb complete

    // ======== C: acc += Cf @ Zb (contract k=(c,t); 32 slots, pads dead via Cf=0) ====
    {
      short8 cf[3];
      #pragma unroll
      for (int m = 0; m < 3; ++m)
        cf[m] = *(const short8*)(Cf + (((((s * 3 + m) * 16 + lc) * 64) + 16 * lq)
                                       ^ ((lc & 3) << 4)));
      #pragma unroll
      for (int i = 0; i < 8; ++i) {
        int px = 16 * (wave + 8 * i) + lc;
        short8 zf = *(const short8*)(Zb + ((px * 64 + 16 * lq) ^ ((px & 3) << 4)));
        acc[0][i] = __builtin_amdgcn_mfma_f32_16x16x32_bf16(cf[0], zf, acc[0][i], 0, 0, 0);
        acc[1][i] = __builtin_amdgcn_mfma_f32_16x16x32_bf16(cf[1], zf, acc[1][i], 0, 0, 0);
        acc[2][i] = __builtin_amdgcn_mfma_f32_16x16x32_bf16(cf[2], zf, acc[2][i], 0, 0, 0);
      }
    }
    __syncthreads();   // C reads done before next chunk's B overwrites Zb
  }

  // ---- epilogue: fully static stores ----
  #pragma unroll
  for (int m = 0; m < 3; ++m)
    #pragma unroll
    for (int i = 0; i < 8; ++i) {
      int n = wave + 8 * i;
      size_t rowbase = (((size_t)(b * 48 + 16 * m + 4 * lq)) * 512 + p * 64 + n) * 512
                       + q * 64 + j0 + lc;
      #pragma unroll
      for (int r = 0; r < 4; ++r)
        out[rowbase + (size_t)r * 262144] = acc[m][i][r];
    }
}

extern "C" void kernel_launch(void* const* d_in, const int* in_sizes, int n_in,
                              void* d_out, int out_size, void* d_ws, size_t ws_size,
                              hipStream_t stream) {
  (void)in_sizes; (void)n_in; (void)d_ws; (void)ws_size; (void)out_size;
  const float* x   = (const float*)d_in[0];
  const float* Ws  = (const float*)d_in[1];
  const float* Hsm = (const float*)d_in[2];
  const float* Cs  = (const float*)d_in[3];
  float* out = (float*)d_out;
  (void)hipFuncSetAttribute((const void*)fpb6,
                            hipFuncAttributeMaxDynamicSharedMemorySize, SMEM_BYTES);
  fpb6<<<dim3(1024), dim3(512), SMEM_BYTES, stream>>>(x, Ws, Hsm, Cs, out);
}

// Round 7
// 177.339 us; speedup vs baseline: 1.1519x; 1.1519x over previous
//
#include <hip/hip_runtime.h>
#include <hip/hip_bf16.h>

// FeatureProcessingBlock: per 64x64 window, Out = sum_t Cs_t^T ( Hs_t^T @ X_c @ Ws_t )
// R7: 1024-thread wg (16 waves, 4/SIMD -> 2x latency hiding), per-thread acc 96->48.
//     Factor frags in LDS (Wf/Hf), Cs gathered from global (L2-hot) during B.
//     Zb [4 kq][1024 px][16B]: linear conflict-free C-reads, ~2-way B-writes.
//     3 phases, 2 barriers/chunk, fin prefetch issued in C(s-1) (dead during B).

typedef __attribute__((ext_vector_type(8))) short short8;
typedef __attribute__((ext_vector_type(4))) short short4v;
typedef __attribute__((ext_vector_type(4))) float float4v;

#define SMEM_BYTES 145408
// Y1F @0:      [3t*8c][2 sv][64 lane][16B] = 49152  (A-output in B-frag layout)
// Zb  @49152:  [4 kq][1024 px][16B] = 65536  (k=c*4+t; kq=c>>1; byte (c&1)*8+2t)
// Hf  @114688: [4 mt][3 t][2 sv][64 lane][16B] = 24576
// Wf  @139264: [3 t][2 sv][64 lane][16B] = 6144

static __device__ __forceinline__ unsigned short f2bf(float f) {
  return __builtin_bit_cast(unsigned short, __float2bfloat16(f));
}

__global__ __launch_bounds__(1024)
void fpb7(const float* __restrict__ x, const float* __restrict__ Ws,
          const float* __restrict__ Hsm, const float* __restrict__ Cs,
          float* __restrict__ out) {
  extern __shared__ char smem[];
  char* Y1F = smem;
  char* Zb  = smem + 49152;
  char* Hf  = smem + 114688;
  char* Wf  = smem + 139264;

  int wid = (blockIdx.x & 7) * 128 + (blockIdx.x >> 3);  // XCD swizzle
  int window = wid >> 2, tile = wid & 3;
  int b = window >> 6, p = (window >> 3) & 7, q = window & 7;
  int j0 = tile * 16;

  int tid = threadIdx.x, lane = tid & 63, wave = tid >> 6;  // wave 0..15
  int lq = lane >> 4, lc = lane & 15;

  int cA  = wave & 7, hh = wave >> 3;   // A-phase: c-in, h-half (mA = 2hh+j2)
  int mtB = wave & 3, cq = wave >> 2;   // B-phase: mt, c-quad (c = 2cq+cj)

  // ---- init: Wf (A-phase B-operand frags of Ws) ----
  if (wave < 6) {
    int t = wave >> 1, sv = wave & 1;
    short8 v;
    #pragma unroll
    for (int e = 0; e < 8; ++e)
      v[e] = (short)f2bf(Ws[t * 4096 + (32 * sv + 8 * lq + e) * 64 + j0 + lc]);
    *(short8*)(Wf + wave * 1024 + lane * 16) = v;
  }
  // ---- init: Hf (B-phase A-operand frags of Hs^T) ----
  for (int j = wave; j < 24; j += 16) {
    int mt = j / 6, r6 = j - 6 * mt, t = r6 >> 1, sv = r6 & 1;
    short8 v;
    #pragma unroll
    for (int e = 0; e < 8; ++e)
      v[e] = (short)f2bf(Hsm[t * 4096 + (32 * sv + 8 * lq + e) * 64 + 16 * mt + lc]);
    *(short8*)(Hf + j * 1024 + lane * 16) = v;
  }

  float4v acc[3][4];
  #pragma unroll
  for (int m = 0; m < 3; ++m)
    #pragma unroll
    for (int i = 0; i < 4; ++i) acc[m][i] = float4v{0.f, 0.f, 0.f, 0.f};

  // A staging base: this wave's c-slice, rows 16*mA+lc, cols 8lq(+32)
  const float* sA = x + (((size_t)b * 48) * 512 + p * 64) * 512 + q * 64
                      + (size_t)cA * 262144 + (size_t)lc * 512 + 8 * lq;

  float4v fin[8];   // [j2*4 + {0,1,2,3}] = cols {8lq,8lq+4,32+8lq,36+8lq}
  #pragma unroll
  for (int j2 = 0; j2 < 2; ++j2) {
    const float* r = sA + (size_t)(2 * hh + j2) * 8192;
    fin[4*j2+0] = *(const float4v*)(r);
    fin[4*j2+1] = *(const float4v*)(r + 4);
    fin[4*j2+2] = *(const float4v*)(r + 32);
    fin[4*j2+3] = *(const float4v*)(r + 36);
  }

  __syncthreads();   // Wf/Hf ready

  for (int s = 0; s < 6; ++s) {
    // ======== A: Y1[t][cA] = X_c @ Ws_t (contract w); frag-major store ========
    {
      short8 af[4];
      #pragma unroll
      for (int j2 = 0; j2 < 2; ++j2) {
        short8 a0, a1;
        #pragma unroll
        for (int e2 = 0; e2 < 4; ++e2) {
          a0[e2]   = (short)f2bf(fin[4*j2+0][e2]);
          a0[4+e2] = (short)f2bf(fin[4*j2+1][e2]);
          a1[e2]   = (short)f2bf(fin[4*j2+2][e2]);
          a1[4+e2] = (short)f2bf(fin[4*j2+3][e2]);
        }
        af[2*j2] = a0; af[2*j2+1] = a1;
      }
      #pragma unroll
      for (int t = 0; t < 3; ++t) {
        short8 wf0 = *(const short8*)(Wf + (t * 2 + 0) * 1024 + lane * 16);
        short8 wf1 = *(const short8*)(Wf + (t * 2 + 1) * 1024 + lane * 16);
        #pragma unroll
        for (int j2 = 0; j2 < 2; ++j2) {
          float4v d = {0.f, 0.f, 0.f, 0.f};
          d = __builtin_amdgcn_mfma_f32_16x16x32_bf16(af[2*j2],   wf0, d, 0, 0, 0);
          d = __builtin_amdgcn_mfma_f32_16x16x32_bf16(af[2*j2+1], wf1, d, 0, 0, 0);
          int lqp = (2 * j2 + (lq >> 1)) & 3;      // (2*mA + lq>>1)&3, mA=2hh+j2
          short4v pv;
          pv[0] = (short)f2bf(d[0]); pv[1] = (short)f2bf(d[1]);
          pv[2] = (short)f2bf(d[2]); pv[3] = (short)f2bf(d[3]);
          *(short4v*)(Y1F + ((t * 8 + cA) * 2 + hh) * 1024
                          + (lqp * 16 + lc) * 16 + (lq & 1) * 8) = pv;
        }
      }
    }
    __syncthreads();   // Y1F complete

    // ======== B: Zb[kq][px] = Hs_t^T @ Y1 (contract h) ========
    {
      // issue Cs gather early (L2-hot; consumed at end of B)
      float craw[3][6];
      #pragma unroll
      for (int m = 0; m < 3; ++m)
        #pragma unroll
        for (int ch = 0; ch < 2; ++ch)
          #pragma unroll
          for (int t = 0; t < 3; ++t)
            craw[m][ch*3+t] =
                Cs[t * 2304 + (8 * s + 2 * lq + ch) * 48 + 16 * m + lc];

      unsigned long long w64[2][4];
      #pragma unroll
      for (int t = 0; t < 3; ++t) {
        short8 hf0 = *(const short8*)(Hf + (mtB * 6 + t * 2 + 0) * 1024 + lane * 16);
        short8 hf1 = *(const short8*)(Hf + (mtB * 6 + t * 2 + 1) * 1024 + lane * 16);
        #pragma unroll
        for (int cj = 0; cj < 2; ++cj) {
          const char* yb = Y1F + ((t * 8 + 2 * cq + cj) * 2) * 1024 + lane * 16;
          short8 y0 = *(const short8*)yb;
          short8 y1 = *(const short8*)(yb + 1024);
          float4v dd = {0.f, 0.f, 0.f, 0.f};
          dd = __builtin_amdgcn_mfma_f32_16x16x32_bf16(hf0, y0, dd, 0, 0, 0);
          dd = __builtin_amdgcn_mfma_f32_16x16x32_bf16(hf1, y1, dd, 0, 0, 0);
          #pragma unroll
          for (int r = 0; r < 4; ++r) {
            unsigned long long v = (unsigned long long)f2bf(dd[r]) << (16 * t);
            if (t == 0) w64[cj][r] = v; else w64[cj][r] |= v;
          }
        }
      }
      #pragma unroll
      for (int cj = 0; cj < 2; ++cj)
        #pragma unroll
        for (int r = 0; r < 4; ++r) {
          int px = (16 * mtB + 4 * lq + r) * 16 + lc;
          *(unsigned long long*)(Zb + cq * 16384 + px * 16 + cj * 8) = w64[cj][r];
        }

      // build cf from craw: k=8lq+e; c=2lq+(e>>2); t=e&3 (t==3 -> 0)
      short8 cf[3];
      #pragma unroll
      for (int m = 0; m < 3; ++m) {
        short8 v;
        v[0] = (short)f2bf(craw[m][0]); v[1] = (short)f2bf(craw[m][1]);
        v[2] = (short)f2bf(craw[m][2]); v[3] = 0;
        v[4] = (short)f2bf(craw[m][3]); v[5] = (short)f2bf(craw[m][4]);
        v[6] = (short)f2bf(craw[m][5]); v[7] = 0;
        cf[m] = v;
      }
      __syncthreads();   // Zb complete

      // ======== C: acc += Cf @ Zb (contract (c,t); linear b128 reads) ========
      if (s < 5) {   // refill fin for chunk s+1 (covers A(s+1))
        #pragma unroll
        for (int j2 = 0; j2 < 2; ++j2) {
          const float* r = sA + (size_t)(s + 1) * 2097152 + (size_t)(2 * hh + j2) * 8192;
          fin[4*j2+0] = *(const float4v*)(r);
          fin[4*j2+1] = *(const float4v*)(r + 4);
          fin[4*j2+2] = *(const float4v*)(r + 32);
          fin[4*j2+3] = *(const float4v*)(r + 36);
        }
      }
      #pragma unroll
      for (int i = 0; i < 4; ++i) {
        int px = (wave + 16 * i) * 16 + lc;
        short8 zf = *(const short8*)(Zb + lq * 16384 + px * 16);
        acc[0][i] = __builtin_amdgcn_mfma_f32_16x16x32_bf16(cf[0], zf, acc[0][i], 0, 0, 0);
        acc[1][i] = __builtin_amdgcn_mfma_f32_16x16x32_bf16(cf[1], zf, acc[1][i], 0, 0, 0);
        acc[2][i] = __builtin_amdgcn_mfma_f32_16x16x32_bf16(cf[2], zf, acc[2][i], 0, 0, 0);
      }
    }
    // next A writes Y1F only after this wave passed bar2 (program order);
    // next B writes Zb only after next bar1 -> C reads are safe with 2 barriers.
  }

  // ---- epilogue: fully static stores ----
  #pragma unroll
  for (int m = 0; m < 3; ++m)
    #pragma unroll
    for (int i = 0; i < 4; ++i) {
      int n = wave + 16 * i;
      #pragma unroll
      for (int r = 0; r < 4; ++r)
        out[(((size_t)(b * 48 + 16 * m + 4 * lq + r)) * 512 + p * 64 + n) * 512
            + q * 64 + j0 + lc] = acc[m][i][r];
    }
}

extern "C" void kernel_launch(void* const* d_in, const int* in_sizes, int n_in,
                              void* d_out, int out_size, void* d_ws, size_t ws_size,
                              hipStream_t stream) {
  (void)in_sizes; (void)n_in; (void)d_ws; (void)ws_size; (void)out_size;
  const float* x   = (const float*)d_in[0];
  const float* Ws  = (const float*)d_in[1];
  const float* Hsm = (const float*)d_in[2];
  const float* Cs  = (const float*)d_in[3];
  float* out = (float*)d_out;
  (void)hipFuncSetAttribute((const void*)fpb7,
                            hipFuncAttributeMaxDynamicSharedMemorySize, SMEM_BYTES);
  fpb7<<<dim3(1024), dim3(1024), SMEM_BYTES, stream>>>(x, Ws, Hsm, Cs, out);
}